// Round 1
// baseline (587.691 us; speedup 1.0000x reference)
//
#include <hip/hip_runtime.h>
#include <float.h>

// Problem constants (from reference setup_inputs)
#define NS   16384   // samples
#define K1   512     // d_in
#define F    256     // n_feat
#define NC   1000    // n_classes
#define NCP  1024    // padded classes
#define SPB  32      // samples per block
#define NTHR 256
#define KC   64      // phase-1 K chunk

// NOTE on numerics: reference computes preds = feats / max(||feats||, eps),
// then argmin(-preds @ means.T). Dividing a row by a positive scalar cannot
// change the argmax of its dot products, so we argmax feats @ means.T
// directly (saves the norm + divide and keeps full fp32 fidelity).
// Tie-break: reference argmin takes the FIRST min => lowest class index wins.

__launch_bounds__(NTHR)
__global__ void fused_cls_kernel(const float* __restrict__ x,
                                 const float* __restrict__ W,
                                 const float* __restrict__ means,
                                 float* __restrict__ out) {
    // LDS: xs 32x68 (8.5 KB) + feats 32x260 (32.5 KB) + bidx
    __shared__ float xs[SPB][KC + 4];
    __shared__ float feats[SPB][F + 4];
    __shared__ int   bidx[SPB];

    const int tid = threadIdx.x;
    const int tn  = tid & 31;   // 32 column groups
    const int ts  = tid >> 5;   // 8 sample groups (4 samples each)
    const int s0  = blockIdx.x * SPB;
    const int n0  = tn * 8;     // phase-1: 8 feature columns per thread

    // ---------------- Phase 1: feats = x[s0:s0+32, :] @ W ----------------
    float acc1[4][8];
#pragma unroll
    for (int i = 0; i < 4; ++i)
#pragma unroll
        for (int n = 0; n < 8; ++n) acc1[i][n] = 0.f;

    for (int kc = 0; kc < K1; kc += KC) {
        // stage x chunk: 32 rows x 64 floats = 512 float4, 2 per thread
#pragma unroll
        for (int p = 0; p < 2; ++p) {
            int q   = tid + p * NTHR;       // 0..511
            int row = q >> 4;               // 16 float4 per row
            int c4  = q & 15;
            float4 v = *reinterpret_cast<const float4*>(
                x + (size_t)(s0 + row) * K1 + kc + c4 * 4);
            *reinterpret_cast<float4*>(&xs[row][c4 * 4]) = v;
        }
        __syncthreads();

#pragma unroll 4
        for (int k4 = 0; k4 < KC / 4; ++k4) {
            float a[4][4];
#pragma unroll
            for (int i = 0; i < 4; ++i) {
                float4 t = *reinterpret_cast<const float4*>(&xs[ts * 4 + i][k4 * 4]);
                a[i][0] = t.x; a[i][1] = t.y; a[i][2] = t.z; a[i][3] = t.w;
            }
            float4 bv[4][2];
#pragma unroll
            for (int j = 0; j < 4; ++j) {
                const float* wp = W + (size_t)(kc + k4 * 4 + j) * F + n0;
                bv[j][0] = *reinterpret_cast<const float4*>(wp);
                bv[j][1] = *reinterpret_cast<const float4*>(wp + 4);
            }
#pragma unroll
            for (int j = 0; j < 4; ++j) {
#pragma unroll
                for (int i = 0; i < 4; ++i) {
                    float av = a[i][j];
                    acc1[i][0] += av * bv[j][0].x;
                    acc1[i][1] += av * bv[j][0].y;
                    acc1[i][2] += av * bv[j][0].z;
                    acc1[i][3] += av * bv[j][0].w;
                    acc1[i][4] += av * bv[j][1].x;
                    acc1[i][5] += av * bv[j][1].y;
                    acc1[i][6] += av * bv[j][1].z;
                    acc1[i][7] += av * bv[j][1].w;
                }
            }
        }
        __syncthreads();
    }

    // park feats in LDS (never goes to HBM)
#pragma unroll
    for (int i = 0; i < 4; ++i)
#pragma unroll
        for (int n = 0; n < 8; ++n)
            feats[ts * 4 + i][n0 + n] = acc1[i][n];
    __syncthreads();

    // ---------------- Phase 2: argmax_c feats . means[c] ----------------
    float bestv[4];
    int   besti[4];
#pragma unroll
    for (int i = 0; i < 4; ++i) { bestv[i] = -FLT_MAX; besti[i] = 0x7FFFFFFF; }

    for (int ct = 0; ct < NCP; ct += 128) {
        int  c[4];
        int  cl[4];
        bool valid[4];
#pragma unroll
        for (int j = 0; j < 4; ++j) {
            c[j]     = ct + tn + 32 * j;     // ascending in j -> tie-break safe
            valid[j] = (c[j] < NC);
            cl[j]    = valid[j] ? c[j] : 0;  // clamp to keep loads in-bounds
        }
        float acc2[4][4];
#pragma unroll
        for (int i = 0; i < 4; ++i)
#pragma unroll
            for (int j = 0; j < 4; ++j) acc2[i][j] = 0.f;

#pragma unroll 4
        for (int k4 = 0; k4 < F / 4; ++k4) {
            float4 av[4];
#pragma unroll
            for (int i = 0; i < 4; ++i)
                av[i] = *reinterpret_cast<const float4*>(&feats[ts * 4 + i][k4 * 4]);
            float4 bv[4];
#pragma unroll
            for (int j = 0; j < 4; ++j)
                bv[j] = *reinterpret_cast<const float4*>(
                    means + (size_t)cl[j] * F + k4 * 4);
#pragma unroll
            for (int i = 0; i < 4; ++i) {
#pragma unroll
                for (int j = 0; j < 4; ++j) {
                    acc2[i][j] += av[i].x * bv[j].x;
                    acc2[i][j] += av[i].y * bv[j].y;
                    acc2[i][j] += av[i].z * bv[j].z;
                    acc2[i][j] += av[i].w * bv[j].w;
                }
            }
        }
#pragma unroll
        for (int i = 0; i < 4; ++i)
#pragma unroll
            for (int j = 0; j < 4; ++j)
                if (valid[j] && acc2[i][j] > bestv[i]) {   // strict > : first max wins
                    bestv[i] = acc2[i][j];
                    besti[i] = c[j];
                }
    }

    // merge across the 32 threads (one half-wave) sharing each sample group
#pragma unroll
    for (int i = 0; i < 4; ++i) {
        float v  = bestv[i];
        int   ix = besti[i];
        for (int off = 16; off; off >>= 1) {
            float ov = __shfl_down(v, off, 32);
            int   oi = __shfl_down(ix, off, 32);
            if (ov > v || (ov == v && oi < ix)) { v = ov; ix = oi; }
        }
        if (tn == 0) bidx[ts * 4 + i] = ix;
    }
    __syncthreads();

    // ---------------- Epilogue: write one-hot rows (full 65.5 MB) --------
    const int NF4 = NC / 4;  // 250 float4 per row
    for (int q = tid; q < SPB * NF4; q += NTHR) {
        int row   = q / NF4;
        int c4    = q - row * NF4;
        int b     = bidx[row];
        int cbase = c4 * 4;
        float4 v;
        v.x = (cbase + 0 == b) ? 1.f : 0.f;
        v.y = (cbase + 1 == b) ? 1.f : 0.f;
        v.z = (cbase + 2 == b) ? 1.f : 0.f;
        v.w = (cbase + 3 == b) ? 1.f : 0.f;
        *reinterpret_cast<float4*>(out + (size_t)(s0 + row) * NC + cbase) = v;
    }
}

extern "C" void kernel_launch(void* const* d_in, const int* in_sizes, int n_in,
                              void* d_out, int out_size, void* d_ws, size_t ws_size,
                              hipStream_t stream) {
    const float* x     = (const float*)d_in[0];
    const float* W     = (const float*)d_in[1];
    const float* means = (const float*)d_in[2];
    float* out         = (float*)d_out;
    fused_cls_kernel<<<NS / SPB, NTHR, 0, stream>>>(x, W, means, out);
}

// Round 2
// 296.217 us; speedup vs baseline: 1.9840x; 1.9840x over previous
//
#include <hip/hip_runtime.h>
#include <float.h>

// Problem constants (from reference setup_inputs)
#define NS   16384   // samples
#define K1   512     // d_in
#define F    256     // n_feat
#define NC   1000    // n_classes
#define SPB  32      // samples per block
#define NTHR 256
#define KC   64      // phase-1 K chunk
#define KC2  8       // phase-2 k-slice of means staged in LDS
#define MSP  12      // padded LDS row stride for means slice (dwords, 16B-aligned)

// NOTE on numerics: reference computes preds = feats / max(||feats||, eps),
// then argmin(-preds @ means.T). Dividing a row by a positive scalar cannot
// change the argmax of its dot products, so we argmax feats @ means.T
// directly. Tie-break: reference argmin takes the FIRST min => lowest class
// index wins (strict > + ascending class order + index-min merge below).

__launch_bounds__(NTHR, 2)
__global__ void fused_cls_kernel(const float* __restrict__ x,
                                 const float* __restrict__ W,
                                 const float* __restrict__ means,
                                 float* __restrict__ out) {
    // LDS budget (exactly 81920 B -> 2 blocks/CU):
    //   U:     49152 B — phase1: xs[32][68]; phase2: ms[1024][MSP]; epilogue: bidx[32]
    //   feats: 32768 B — persistent across phases
    __shared__ __align__(16) float U[1024 * MSP];
    __shared__ __align__(16) float feats[SPB][F];

    const int tid = threadIdx.x;
    const int s0  = blockIdx.x * SPB;

    // ================= Phase 1: feats = x[s0:s0+32, :] @ W =================
    {
        float (*xs)[KC + 4] = reinterpret_cast<float (*)[KC + 4]>(U);  // 32x68
        const int tn = tid & 31;   // 32 column groups
        const int ts = tid >> 5;   // 8 sample groups (4 samples each)
        const int n0 = tn * 8;     // 8 feature columns per thread

        float acc1[4][8];
#pragma unroll
        for (int i = 0; i < 4; ++i)
#pragma unroll
            for (int n = 0; n < 8; ++n) acc1[i][n] = 0.f;

        for (int kc = 0; kc < K1; kc += KC) {
            // stage x chunk: 32 rows x 64 floats = 512 float4, 2 per thread
#pragma unroll
            for (int p = 0; p < 2; ++p) {
                int q   = tid + p * NTHR;       // 0..511
                int row = q >> 4;               // 16 float4 per row
                int c4  = q & 15;
                float4 v = *reinterpret_cast<const float4*>(
                    x + (size_t)(s0 + row) * K1 + kc + c4 * 4);
                *reinterpret_cast<float4*>(&xs[row][c4 * 4]) = v;
            }
            __syncthreads();

#pragma unroll 4
            for (int k4 = 0; k4 < KC / 4; ++k4) {
                float a[4][4];
#pragma unroll
                for (int i = 0; i < 4; ++i) {
                    float4 t = *reinterpret_cast<const float4*>(&xs[ts * 4 + i][k4 * 4]);
                    a[i][0] = t.x; a[i][1] = t.y; a[i][2] = t.z; a[i][3] = t.w;
                }
                float4 bv[4][2];
#pragma unroll
                for (int j = 0; j < 4; ++j) {
                    const float* wp = W + (size_t)(kc + k4 * 4 + j) * F + n0;
                    bv[j][0] = *reinterpret_cast<const float4*>(wp);
                    bv[j][1] = *reinterpret_cast<const float4*>(wp + 4);
                }
#pragma unroll
                for (int j = 0; j < 4; ++j) {
#pragma unroll
                    for (int i = 0; i < 4; ++i) {
                        float av = a[i][j];
                        acc1[i][0] += av * bv[j][0].x;
                        acc1[i][1] += av * bv[j][0].y;
                        acc1[i][2] += av * bv[j][0].z;
                        acc1[i][3] += av * bv[j][0].w;
                        acc1[i][4] += av * bv[j][1].x;
                        acc1[i][5] += av * bv[j][1].y;
                        acc1[i][6] += av * bv[j][1].z;
                        acc1[i][7] += av * bv[j][1].w;
                    }
                }
            }
            __syncthreads();
        }

        // park feats in LDS (never goes to HBM)
#pragma unroll
        for (int i = 0; i < 4; ++i)
#pragma unroll
            for (int n = 0; n < 8; ++n)
                feats[ts * 4 + i][n0 + n] = acc1[i][n];
        __syncthreads();
    }

    // ========== Phase 2: scores = feats @ means.T, running argmax ==========
    // Wave w (tr = tid>>6) owns samples tr*8..tr*8+7 vs ALL 1024 class slots.
    // Lane tc (tid&63) owns classes tc + 64*j, j = 0..15.
    const int tc = tid & 63;
    const int tr = tid >> 6;

    float acc[2][8][8];   // [jh][sample i][j8] — 128 persistent accumulators
#pragma unroll
    for (int jh = 0; jh < 2; ++jh)
#pragma unroll
        for (int i = 0; i < 8; ++i)
#pragma unroll
            for (int j = 0; j < 8; ++j) acc[jh][i][j] = 0.f;

    float* ms = U;  // ms[1024][MSP], k-slice of means, padded stride 12

    for (int st = 0; st < F / KC2; ++st) {   // 32 k-slices of 8
        const int kc0 = st * KC2;
        // stage means[:, kc0:kc0+8] -> ms: 1024 rows x 2 float4 = 8/thread
#pragma unroll
        for (int p = 0; p < 8; ++p) {
            int q = tid + p * NTHR;          // 0..2047
            int r = q >> 1;
            int h = q & 1;
            int r_ld = (r < NC) ? r : 0;     // clamp OOB rows (masked later)
            float4 v = *reinterpret_cast<const float4*>(
                means + (size_t)r_ld * F + kc0 + h * 4);
            *reinterpret_cast<float4*>(&ms[r * MSP + h * 4]) = v;
        }
        __syncthreads();

#pragma unroll
        for (int k4 = 0; k4 < KC2 / 4; ++k4) {   // 2 iters
            float4 av[8];                        // full-wave broadcast reads
#pragma unroll
            for (int i = 0; i < 8; ++i)
                av[i] = *reinterpret_cast<const float4*>(
                    &feats[tr * 8 + i][kc0 + k4 * 4]);
#pragma unroll
            for (int jh = 0; jh < 2; ++jh) {
                float4 bv[8];
#pragma unroll
                for (int j = 0; j < 8; ++j)
                    bv[j] = *reinterpret_cast<const float4*>(
                        &ms[(tc + 64 * (jh * 8 + j)) * MSP + k4 * 4]);
#pragma unroll
                for (int i = 0; i < 8; ++i)
#pragma unroll
                    for (int j = 0; j < 8; ++j) {
                        acc[jh][i][j] += av[i].x * bv[j].x;
                        acc[jh][i][j] += av[i].y * bv[j].y;
                        acc[jh][i][j] += av[i].z * bv[j].z;
                        acc[jh][i][j] += av[i].w * bv[j].w;
                    }
            }
        }
        __syncthreads();
    }

    // ---- argmax finalize: per-lane over j (ascending), then 64-lane merge ----
    int* bidx = reinterpret_cast<int*>(U);   // ms reads all done (barrier above)
#pragma unroll
    for (int i = 0; i < 8; ++i) {
        float v  = -FLT_MAX;
        int   ix = 0x7FFFFFFF;
#pragma unroll
        for (int j = 0; j < 16; ++j) {
            int c = tc + 64 * j;
            if (c < NC) {
                float s = acc[j >> 3][i][j & 7];
                if (s > v) { v = s; ix = c; }    // strict >: first (lowest c) wins
            }
        }
        for (int off = 32; off; off >>= 1) {
            float ov = __shfl_down(v, off, 64);
            int   oi = __shfl_down(ix, off, 64);
            if (ov > v || (ov == v && oi < ix)) { v = ov; ix = oi; }
        }
        if (tc == 0) bidx[tr * 8 + i] = ix;
    }
    __syncthreads();

    // ================= Epilogue: write one-hot rows =================
    const int NF4 = NC / 4;  // 250 float4 per row
    for (int q = tid; q < SPB * NF4; q += NTHR) {
        int row   = q / NF4;
        int c4    = q - row * NF4;
        int b     = bidx[row];
        int cbase = c4 * 4;
        float4 v;
        v.x = (cbase + 0 == b) ? 1.f : 0.f;
        v.y = (cbase + 1 == b) ? 1.f : 0.f;
        v.z = (cbase + 2 == b) ? 1.f : 0.f;
        v.w = (cbase + 3 == b) ? 1.f : 0.f;
        *reinterpret_cast<float4*>(out + (size_t)(s0 + row) * NC + cbase) = v;
    }
}

extern "C" void kernel_launch(void* const* d_in, const int* in_sizes, int n_in,
                              void* d_out, int out_size, void* d_ws, size_t ws_size,
                              hipStream_t stream) {
    const float* x     = (const float*)d_in[0];
    const float* W     = (const float*)d_in[1];
    const float* means = (const float*)d_in[2];
    float* out         = (float*)d_out;
    fused_cls_kernel<<<NS / SPB, NTHR, 0, stream>>>(x, W, means, out);
}

// Round 3
// 288.945 us; speedup vs baseline: 2.0339x; 1.0252x over previous
//
#include <hip/hip_runtime.h>
#include <float.h>

// Problem constants (from reference setup_inputs)
#define NS   16384   // samples
#define K1   512     // d_in
#define F    256     // n_feat
#define NC   1000    // n_classes
#define NCP  1024    // padded classes
#define SPB  32      // samples per block
#define NTHR 256
#define KC   64      // phase-1 K chunk
#define NSL  (F / 4) // 64 phase-2 k-slices of 4

// NOTE on numerics: preds = feats / max(||feats||,eps) divides each row by a
// positive scalar => argmax(preds@means.T) == argmax(feats@means.T). We skip
// the normalization. Tie-break: reference argmin takes FIRST min => lowest
// class index wins (strict > per-lane ascending + index-min merge).

// -------- prep: means4[s][c][0..3] = means[c][4s+k], zero-pad c>=NC --------
__global__ void prep_means(const float* __restrict__ means,
                           float* __restrict__ means4) {
    int t = blockIdx.x * blockDim.x + threadIdx.x;  // 65536 threads (s,c)
    int s = t >> 10;        // 0..63
    int c = t & 1023;       // 0..1023
    float4 v = make_float4(0.f, 0.f, 0.f, 0.f);
    if (c < NC) v = *reinterpret_cast<const float4*>(means + (size_t)c * F + s * 4);
    *reinterpret_cast<float4*>(means4 + ((size_t)s * NCP + c) * 4) = v;
}

__launch_bounds__(NTHR, 2)
__global__ void fused_cls_kernel(const float* __restrict__ x,
                                 const float* __restrict__ W,
                                 const float* __restrict__ means4,
                                 float* __restrict__ out) {
    // LDS: msbuf 2x16KB (ping-pong; phase-1 xs + bidx unioned in) + feats 32KB
    __shared__ __align__(16) float msbuf[2][NCP * 4];
    __shared__ __align__(16) float feats[SPB][F];

    const int tid = threadIdx.x;
    const int s0  = blockIdx.x * SPB;

    // ================= Phase 1: feats = x[s0:s0+32, :] @ W =================
    {
        const int tn = tid & 31;   // 32 column groups
        const int ts = tid >> 5;   // 8 sample groups (4 samples each)
        const int n0 = tn * 8;     // 8 feature columns per thread
        const int xrow = tid >> 4;         // staging: row 0..31
        const int xc4  = (tid & 15) * 4;   // float4 col within chunk

        float acc1[4][8];
#pragma unroll
        for (int i = 0; i < 4; ++i)
#pragma unroll
            for (int n = 0; n < 8; ++n) acc1[i][n] = 0.f;

        // preload chunk 0 (2 float4 per thread: rows xrow and xrow+... q=tid+256)
        float4 xr[2];
#pragma unroll
        for (int p = 0; p < 2; ++p) {
            int q = tid + p * NTHR;
            xr[p] = *reinterpret_cast<const float4*>(
                x + (size_t)(s0 + (q >> 4)) * K1 + (q & 15) * 4);
        }

        for (int kc8 = 0; kc8 < K1 / KC; ++kc8) {
            float (*xs)[KC + 4] = reinterpret_cast<float (*)[KC + 4]>(msbuf[kc8 & 1]);
            // ds_write staged regs (conflict pattern benign; ping-pong, 1 barrier)
#pragma unroll
            for (int p = 0; p < 2; ++p) {
                int q = tid + p * NTHR;
                *reinterpret_cast<float4*>(&xs[q >> 4][(q & 15) * 4]) = xr[p];
            }
            __syncthreads();
            if (kc8 + 1 < K1 / KC) {
#pragma unroll
                for (int p = 0; p < 2; ++p) {
                    int q = tid + p * NTHR;
                    xr[p] = *reinterpret_cast<const float4*>(
                        x + (size_t)(s0 + (q >> 4)) * K1 + (kc8 + 1) * KC + (q & 15) * 4);
                }
            }
            const int kc = kc8 * KC;
#pragma unroll 4
            for (int k4 = 0; k4 < KC / 4; ++k4) {
                float a[4][4];
#pragma unroll
                for (int i = 0; i < 4; ++i) {
                    float4 t = *reinterpret_cast<const float4*>(&xs[ts * 4 + i][k4 * 4]);
                    a[i][0] = t.x; a[i][1] = t.y; a[i][2] = t.z; a[i][3] = t.w;
                }
                float4 bw[4][2];
#pragma unroll
                for (int j = 0; j < 4; ++j) {
                    const float* wp = W + (size_t)(kc + k4 * 4 + j) * F + n0;
                    bw[j][0] = *reinterpret_cast<const float4*>(wp);
                    bw[j][1] = *reinterpret_cast<const float4*>(wp + 4);
                }
#pragma unroll
                for (int j = 0; j < 4; ++j) {
#pragma unroll
                    for (int i = 0; i < 4; ++i) {
                        float av = a[i][j];
                        acc1[i][0] += av * bw[j][0].x;
                        acc1[i][1] += av * bw[j][0].y;
                        acc1[i][2] += av * bw[j][0].z;
                        acc1[i][3] += av * bw[j][0].w;
                        acc1[i][4] += av * bw[j][1].x;
                        acc1[i][5] += av * bw[j][1].y;
                        acc1[i][6] += av * bw[j][1].z;
                        acc1[i][7] += av * bw[j][1].w;
                    }
                }
            }
            // no trailing barrier: next iter writes the OTHER buffer
        }

        // park feats in LDS (never goes to HBM)
#pragma unroll
        for (int i = 0; i < 4; ++i)
#pragma unroll
            for (int n = 0; n < 8; ++n)
                feats[ts * 4 + i][n0 + n] = acc1[i][n];
        __syncthreads();
    }

    // ========== Phase 2: scores = feats @ means.T, running argmax ==========
    // Wave tr owns samples tr*8..tr*8+7 vs all 1024 class slots.
    // Lane tc owns classes tc + 64*j, j = 0..15 (ascending => tie-break safe).
    const int tc = tid & 63;
    const int tr = tid >> 6;

    float acc[2][8][8];
#pragma unroll
    for (int jh = 0; jh < 2; ++jh)
#pragma unroll
        for (int i = 0; i < 8; ++i)
#pragma unroll
            for (int j = 0; j < 8; ++j) acc[jh][i][j] = 0.f;

    // preload slice 0: 4 coalesced float4 per thread (classes tid+256p)
    float4 mr[4];
#pragma unroll
    for (int p = 0; p < 4; ++p)
        mr[p] = *reinterpret_cast<const float4*>(
            means4 + ((size_t)0 * NCP + tid + 256 * p) * 4);

    for (int s = 0; s < NSL; ++s) {
        float* ms = msbuf[s & 1];
        // conflict-free ds_write: lane->row identity, stride 4 dwords
#pragma unroll
        for (int p = 0; p < 4; ++p)
            *reinterpret_cast<float4*>(&ms[(tid + 256 * p) * 4]) = mr[p];
        __syncthreads();
        if (s + 1 < NSL) {
#pragma unroll
            for (int p = 0; p < 4; ++p)
                mr[p] = *reinterpret_cast<const float4*>(
                    means4 + ((size_t)(s + 1) * NCP + tid + 256 * p) * 4);
        }

        float4 av[8];   // full-wave broadcast reads
#pragma unroll
        for (int i = 0; i < 8; ++i)
            av[i] = *reinterpret_cast<const float4*>(&feats[tr * 8 + i][s * 4]);
#pragma unroll
        for (int jh = 0; jh < 2; ++jh) {
            float4 bv[8];   // contiguous 1KB wave reads, conflict-free
#pragma unroll
            for (int j = 0; j < 8; ++j)
                bv[j] = *reinterpret_cast<const float4*>(
                    &ms[(tc + 64 * (jh * 8 + j)) * 4]);
#pragma unroll
            for (int i = 0; i < 8; ++i)
#pragma unroll
                for (int j = 0; j < 8; ++j) {
                    acc[jh][i][j] += av[i].x * bv[j].x;
                    acc[jh][i][j] += av[i].y * bv[j].y;
                    acc[jh][i][j] += av[i].z * bv[j].z;
                    acc[jh][i][j] += av[i].w * bv[j].w;
                }
        }
        // no trailing barrier: next iter writes the other buffer
    }

    // ---- argmax: per-lane over j (ascending), then 64-lane top merge ----
    int* bidx = reinterpret_cast<int*>(msbuf[0]);
#pragma unroll
    for (int i = 0; i < 8; ++i) {
        float v  = -FLT_MAX;
        int   ix = 0x7FFFFFFF;
#pragma unroll
        for (int j = 0; j < 16; ++j) {
            int c = tc + 64 * j;
            if (c < NC) {
                float sc = acc[j >> 3][i][j & 7];
                if (sc > v) { v = sc; ix = c; }   // strict >: first (lowest c) wins
            }
        }
        for (int off = 32; off; off >>= 1) {
            float ov = __shfl_down(v, off, 64);
            int   oi = __shfl_down(ix, off, 64);
            if (ov > v || (ov == v && oi < ix)) { v = ov; ix = oi; }
        }
        if (tc == 0) bidx[tr * 8 + i] = ix;
    }
    __syncthreads();

    // ================= Epilogue: write one-hot rows =================
    const int NF4 = NC / 4;  // 250 float4 per row
    for (int q = tid; q < SPB * NF4; q += NTHR) {
        int row   = q / NF4;
        int c4    = q - row * NF4;
        int b     = bidx[row];
        int cbase = c4 * 4;
        float4 v;
        v.x = (cbase + 0 == b) ? 1.f : 0.f;
        v.y = (cbase + 1 == b) ? 1.f : 0.f;
        v.z = (cbase + 2 == b) ? 1.f : 0.f;
        v.w = (cbase + 3 == b) ? 1.f : 0.f;
        *reinterpret_cast<float4*>(out + (size_t)(s0 + row) * NC + cbase) = v;
    }
}

extern "C" void kernel_launch(void* const* d_in, const int* in_sizes, int n_in,
                              void* d_out, int out_size, void* d_ws, size_t ws_size,
                              hipStream_t stream) {
    const float* x     = (const float*)d_in[0];
    const float* W     = (const float*)d_in[1];
    const float* means = (const float*)d_in[2];
    float* out         = (float*)d_out;
    float* means4      = (float*)d_ws;   // 64*1024*4 floats = 1 MB

    prep_means<<<(64 * NCP) / NTHR, NTHR, 0, stream>>>(means, means4);
    fused_cls_kernel<<<NS / SPB, NTHR, 0, stream>>>(x, W, means4, out);
}